// Round 1
// baseline (1263.362 us; speedup 1.0000x reference)
//
#include <hip/hip_runtime.h>
#include <hip/hip_bf16.h>
#include <math.h>

#define N_NODES 50000
#define N_EDGES 600000
// IN_DIM=128, EDGE_DIM=64, PRE_K=320, POST_K=1664, OUT=128

typedef __attribute__((ext_vector_type(8))) short short8v;   // 8 bf16 (4 VGPR) MFMA A/B frag
typedef __attribute__((ext_vector_type(4))) short short4v;
typedef __attribute__((ext_vector_type(4))) float f32x4;     // MFMA C/D frag
typedef __attribute__((ext_vector_type(4))) float float4v;
typedef __attribute__((ext_vector_type(4))) unsigned int uint4v;

__device__ __forceinline__ short f2bf(float f) {
  unsigned int u = __float_as_uint(f);
  u = (u + 0x7FFFu + ((u >> 16) & 1u)) >> 16;   // RNE
  return (short)u;
}

// ---- init: mn plane = +inf --------------------------------------------------
__global__ void fill_mn_kernel(unsigned int* __restrict__ mn, long n4) {
  long i = (long)blockIdx.x * blockDim.x + threadIdx.x;
  long stride = (long)gridDim.x * blockDim.x;
  uint4v v = {0x7F800000u, 0x7F800000u, 0x7F800000u, 0x7F800000u};
  for (; i < n4; i += stride) ((uint4v*)mn)[i] = v;
}

// ---- node_feat f32 -> bf16 table -------------------------------------------
__global__ void conv_node_kernel(const float* __restrict__ nf, short* __restrict__ nb, long n4) {
  long i = (long)blockIdx.x * blockDim.x + threadIdx.x;
  long stride = (long)gridDim.x * blockDim.x;
  for (; i < n4; i += stride) {
    float4v v = ((const float4v*)nf)[i];
    short4v s;
    s[0] = f2bf(v[0]); s[1] = f2bf(v[1]); s[2] = f2bf(v[2]); s[3] = f2bf(v[3]);
    ((short4v*)nb)[i] = s;
  }
}

// ---- weights: transpose to [n][k] row-major bf16 ---------------------------
__global__ void conv_w_kernel(const float* __restrict__ Wpre, const float* __restrict__ Wp1,
                              const float* __restrict__ Wp2, short* __restrict__ WpreT,
                              short* __restrict__ Wp1T, short* __restrict__ Wp2T) {
  int idx = blockIdx.x * 256 + threadIdx.x;
  if (idx < 128 * 320) {
    int n = idx / 320, k = idx % 320;
    WpreT[idx] = f2bf(Wpre[k * 128 + n]);
  } else if (idx < 128 * 320 + 128 * 1664) {
    int o = idx - 128 * 320;
    int n = o / 1664, k = o % 1664;
    Wp1T[o] = f2bf(Wp1[k * 128 + n]);
  } else if (idx < 128 * 320 + 128 * 1664 + 128 * 128) {
    int o = idx - (128 * 320 + 128 * 1664);
    int n = o / 128, k = o % 128;
    Wp2T[o] = f2bf(Wp2[k * 128 + n]);
  }
}

// ---- degree histogram ------------------------------------------------------
__global__ void deg_kernel(const int* __restrict__ dst, int* __restrict__ deg) {
  int i = blockIdx.x * blockDim.x + threadIdx.x;
  int stride = gridDim.x * blockDim.x;
  for (; i < N_EDGES; i += stride) atomicAdd(deg + dst[i], 1);
}

// ---- edge kernel: e = relu([x_src|x_dst|ef] @ W_pre + b), scatter-aggregate
// Weight-stationary: each wave holds W_preT frags for its 2 n-tiles in 80 VGPRs.
// 32 edges per chunk staged in LDS (stride 328 bf16 to dodge bank conflicts).
__global__ __launch_bounds__(256) void edge_kernel(
    const int* __restrict__ src, const int* __restrict__ dst,
    const float* __restrict__ edge_feat, const float* __restrict__ b_pre,
    const short* __restrict__ node_bf, const short* __restrict__ WpreT,
    float* __restrict__ sum, float* __restrict__ sq,
    unsigned int* __restrict__ mx, unsigned int* __restrict__ mn) {
  __shared__ short A[32][328];   // 32 edges x 320 (pad 8)
  __shared__ int dstl[32];
  int t = threadIdx.x;
  int lane = t & 63, w = t >> 6;
  int r15 = lane & 15, g = lane >> 4;

  // preload B fragments: wave w owns n-tiles {2w, 2w+1}
  short8v bfr[10][2];
#pragma unroll
  for (int ks = 0; ks < 10; ks++)
#pragma unroll
    for (int j = 0; j < 2; j++) {
      const short* p = WpreT + (size_t)((2 * w + j) * 16 + r15) * 320 + ks * 32 + 8 * g;
      bfr[ks][j] = *(const short8v*)p;
    }
  float bp[2];
  bp[0] = b_pre[2 * w * 16 + r15];
  bp[1] = b_pre[(2 * w + 1) * 16 + r15];

  const int nchunks = N_EDGES / 32;  // 18750, exact
  for (int ch = blockIdx.x; ch < nchunks; ch += gridDim.x) {
    int e0 = ch * 32;
    // gather src|dst rows (bf16, 512B per edge) : 1024 x 16B units
#pragma unroll
    for (int i = 0; i < 4; i++) {
      int u = t + 256 * i;
      int e = u >> 5, off16 = u & 31;
      int eg = e0 + e;
      int idx = (off16 < 16) ? src[eg] : dst[eg];
      int col16 = off16 & 15;
      int4 v = *(const int4*)(node_bf + (size_t)idx * 128 + col16 * 8);
      *(int4*)(&A[e][off16 * 8]) = v;
    }
    // edge_feat f32 -> bf16 : 512 x 4-float units
#pragma unroll
    for (int i = 0; i < 2; i++) {
      int u = t + 256 * i;
      int e = u >> 4, c4 = (u & 15) * 4;
      float4v v = *(const float4v*)(edge_feat + (size_t)(e0 + e) * 64 + c4);
      short4v s;
      s[0] = f2bf(v[0]); s[1] = f2bf(v[1]); s[2] = f2bf(v[2]); s[3] = f2bf(v[3]);
      *(short4v*)(&A[e][256 + c4]) = s;
    }
    if (t < 32) dstl[t] = dst[e0 + t];
    __syncthreads();

    f32x4 acc[2][2];
#pragma unroll
    for (int m = 0; m < 2; m++)
#pragma unroll
      for (int j = 0; j < 2; j++) acc[m][j] = (f32x4){0.f, 0.f, 0.f, 0.f};

#pragma unroll
    for (int m = 0; m < 2; m++)
#pragma unroll
      for (int ks = 0; ks < 10; ks++) {
        short8v af = *(const short8v*)(&A[m * 16 + r15][ks * 32 + 8 * g]);
        acc[m][0] = __builtin_amdgcn_mfma_f32_16x16x32_bf16(af, bfr[ks][0], acc[m][0], 0, 0, 0);
        acc[m][1] = __builtin_amdgcn_mfma_f32_16x16x32_bf16(af, bfr[ks][1], acc[m][1], 0, 0, 0);
      }

    // epilogue: bias+relu, scatter into 4 aggregate planes
#pragma unroll
    for (int m = 0; m < 2; m++)
#pragma unroll
      for (int j = 0; j < 2; j++)
#pragma unroll
        for (int r = 0; r < 4; r++) {
          float v = fmaxf(acc[m][j][r] + bp[j], 0.f);
          int erow = m * 16 + 4 * g + r;
          int d = dstl[erow];
          int col = (2 * w + j) * 16 + r15;
          size_t o = (size_t)d * 128 + col;
          atomicAdd(sum + o, v);
          atomicAdd(sq + o, v * v);
          atomicMax(mx + o, __float_as_uint(v));  // v>=0 so uint order == float order
          atomicMin(mn + o, __float_as_uint(v));
        }
    __syncthreads();
  }
}

// ---- post kernel: build h[1664] on the fly, 2-layer MLP + residual ---------
__global__ __launch_bounds__(256) void post_kernel(
    const float* __restrict__ node_feat, const int* __restrict__ deg,
    const float* __restrict__ sum, const float* __restrict__ sq,
    const float* __restrict__ mxp, const float* __restrict__ mnp,
    const short* __restrict__ Wp1T, const short* __restrict__ Wp2T,
    const float* __restrict__ b1, const float* __restrict__ b2,
    float* __restrict__ out) {
  __shared__ short Ak[64][40];    // 64 nodes x 32 k (pad 8)
  __shared__ short T[64][136];    // relu(h@W1+b1) bf16 (pad 8)
  __shared__ float scal[64][4];   // inv_safe_deg, logd/2.5, att_factor, has_edges
  int t = threadIdx.x;
  int lane = t & 63, w = t >> 6;
  int r15 = lane & 15, g = lane >> 4;
  int nb = blockIdx.x * 64;

  if (t < 64) {
    int n = min(nb + t, N_NODES - 1);
    float dg = (float)deg[n];
    scal[t][0] = 1.f / fmaxf(dg, 1.f);
    float logd = logf(dg + 1.f);
    scal[t][1] = logd * 0.4f;                                  // /2.5
    scal[t][2] = (dg > 0.f) ? 2.5f / fmaxf(logd, 1e-5f) : 0.f;
    scal[t][3] = (dg > 0.f) ? 1.f : 0.f;
  }
  __syncthreads();

  f32x4 acc1[4][2];
#pragma unroll
  for (int m = 0; m < 4; m++)
#pragma unroll
    for (int j = 0; j < 2; j++) acc1[m][j] = (f32x4){0.f, 0.f, 0.f, 0.f};

  for (int ks = 0; ks < 52; ks++) {
    int k0 = ks * 32;
    int seg = k0 >> 7;     // uniform per k-step (32 | 128)
    int cbase = k0 & 127;
#pragma unroll
    for (int jj = 0; jj < 8; jj++) {
      int vi = t + 256 * jj;
      int nd = vi >> 5, c = vi & 31;
      int gn = min(nb + nd, N_NODES - 1);
      int col = cbase + c;
      float v;
      if (seg == 0) {
        v = node_feat[(size_t)gn * 128 + col];
      } else {
        int si = (seg - 1) & 3, sc = (seg - 1) >> 2;
        size_t o = (size_t)gn * 128 + col;
        float stat;
        if (si == 0) {
          stat = sum[o] * scal[nd][0];                               // mean
        } else if (si == 1) {
          stat = mxp[o];                                             // max (0 if no edges)
        } else if (si == 2) {
          stat = (scal[nd][3] != 0.f) ? mnp[o] : 0.f;                // min (gate +inf)
        } else {
          float mean = sum[o] * scal[nd][0];
          float ms = sq[o] * scal[nd][0];
          stat = scal[nd][3] * sqrtf(fmaxf(ms - mean * mean, 0.f) + 1e-5f);  // std
        }
        float f = (sc == 0) ? 1.f : ((sc == 1) ? scal[nd][1] : scal[nd][2]);
        v = stat * f;
      }
      Ak[nd][c] = f2bf(v);
    }
    __syncthreads();
    short8v af[4], bfr[2];
#pragma unroll
    for (int m = 0; m < 4; m++) af[m] = *(const short8v*)(&Ak[m * 16 + r15][8 * g]);
#pragma unroll
    for (int j = 0; j < 2; j++)
      bfr[j] = *(const short8v*)(Wp1T + (size_t)((2 * w + j) * 16 + r15) * 1664 + k0 + 8 * g);
#pragma unroll
    for (int m = 0; m < 4; m++)
#pragma unroll
      for (int j = 0; j < 2; j++)
        acc1[m][j] = __builtin_amdgcn_mfma_f32_16x16x32_bf16(af[m], bfr[j], acc1[m][j], 0, 0, 0);
    __syncthreads();
  }

  float bb1[2];
  bb1[0] = b1[2 * w * 16 + r15];
  bb1[1] = b1[(2 * w + 1) * 16 + r15];
#pragma unroll
  for (int m = 0; m < 4; m++)
#pragma unroll
    for (int j = 0; j < 2; j++)
#pragma unroll
      for (int r = 0; r < 4; r++) {
        float v = fmaxf(acc1[m][j][r] + bb1[j], 0.f);
        T[m * 16 + 4 * g + r][(2 * w + j) * 16 + r15] = f2bf(v);
      }
  __syncthreads();

  f32x4 acc2[4][2];
#pragma unroll
  for (int m = 0; m < 4; m++)
#pragma unroll
    for (int j = 0; j < 2; j++) acc2[m][j] = (f32x4){0.f, 0.f, 0.f, 0.f};
#pragma unroll
  for (int ks = 0; ks < 4; ks++) {
    short8v af2[4], b2f[2];
#pragma unroll
    for (int m = 0; m < 4; m++) af2[m] = *(const short8v*)(&T[m * 16 + r15][ks * 32 + 8 * g]);
#pragma unroll
    for (int j = 0; j < 2; j++)
      b2f[j] = *(const short8v*)(Wp2T + (size_t)((2 * w + j) * 16 + r15) * 128 + ks * 32 + 8 * g);
#pragma unroll
    for (int m = 0; m < 4; m++)
#pragma unroll
      for (int j = 0; j < 2; j++)
        acc2[m][j] = __builtin_amdgcn_mfma_f32_16x16x32_bf16(af2[m], b2f[j], acc2[m][j], 0, 0, 0);
  }

#pragma unroll
  for (int m = 0; m < 4; m++)
#pragma unroll
    for (int j = 0; j < 2; j++)
#pragma unroll
      for (int r = 0; r < 4; r++) {
        int row = m * 16 + 4 * g + r;
        int gn = nb + row;
        if (gn < N_NODES) {
          int col = (2 * w + j) * 16 + r15;
          size_t o = (size_t)gn * 128 + col;
          out[o] = acc2[m][j][r] + b2[col] + node_feat[o];
        }
      }
}

extern "C" void kernel_launch(void* const* d_in, const int* in_sizes, int n_in,
                              void* d_out, int out_size, void* d_ws, size_t ws_size,
                              hipStream_t stream) {
  const float* node_feat = (const float*)d_in[0];
  const float* edge_feat = (const float*)d_in[1];
  const int* src = (const int*)d_in[2];
  const int* dst = (const int*)d_in[3];
  const float* W_pre = (const float*)d_in[4];
  const float* b_pre = (const float*)d_in[5];
  const float* W_post1 = (const float*)d_in[6];
  const float* b_post1 = (const float*)d_in[7];
  const float* W_post2 = (const float*)d_in[8];
  const float* b_post2 = (const float*)d_in[9];
  float* out = (float*)d_out;

  char* ws = (char*)d_ws;
  size_t P = (size_t)N_NODES * 128;
  float* sum = (float*)ws;
  float* sq = sum + P;
  float* mx = sq + P;
  float* mn = mx + P;
  int* deg = (int*)(mn + P);
  short* node_bf = (short*)(deg + ((N_NODES + 63) & ~63));
  short* WpreT = node_bf + P;
  short* Wp1T = WpreT + 128 * 320;
  short* Wp2T = Wp1T + 128 * 1664;
  size_t needed = (size_t)((char*)(Wp2T + 128 * 128) - ws);
  if (ws_size < needed) return;  // clean failure signal instead of OOB

  hipMemsetAsync(sum, 0, 3 * P * sizeof(float), stream);  // sum, sq, mx
  hipMemsetAsync(deg, 0, N_NODES * sizeof(int), stream);
  fill_mn_kernel<<<2048, 256, 0, stream>>>((unsigned int*)mn, (long)(P / 4));
  conv_node_kernel<<<2048, 256, 0, stream>>>(node_feat, node_bf, (long)(P / 4));
  conv_w_kernel<<<(128 * 320 + 128 * 1664 + 128 * 128 + 255) / 256, 256, 0, stream>>>(
      W_pre, W_post1, W_post2, WpreT, Wp1T, Wp2T);
  deg_kernel<<<1024, 256, 0, stream>>>(dst, deg);
  edge_kernel<<<1536, 256, 0, stream>>>(src, dst, edge_feat, b_pre, node_bf, WpreT, sum, sq,
                                        (unsigned int*)mx, (unsigned int*)mn);
  post_kernel<<<(N_NODES + 63) / 64, 256, 0, stream>>>(node_feat, deg, sum, sq, mx, mn, Wp1T,
                                                       Wp2T, b_post1, b_post2, out);
}

// Round 2
// 729.829 us; speedup vs baseline: 1.7310x; 1.7310x over previous
//
#include <hip/hip_runtime.h>
#include <hip/hip_bf16.h>
#include <math.h>

#define N_NODES 50000
#define N_EDGES 600000
// IN_DIM=128, EDGE_DIM=64, PRE_K=320, POST_K=1664, OUT=128

typedef __attribute__((ext_vector_type(8))) short short8v;   // 8 bf16 (4 VGPR) MFMA A/B frag
typedef __attribute__((ext_vector_type(4))) short short4v;
typedef __attribute__((ext_vector_type(4))) float f32x4;     // MFMA C/D frag
typedef __attribute__((ext_vector_type(4))) float float4v;
typedef __attribute__((ext_vector_type(4))) unsigned int uint4v;

__device__ __forceinline__ short f2bf(float f) {
  unsigned int u = __float_as_uint(f);
  u = (u + 0x7FFFu + ((u >> 16) & 1u)) >> 16;   // RNE
  return (short)u;
}

// ---- init: mn plane = +inf --------------------------------------------------
__global__ void fill_mn_kernel(unsigned int* __restrict__ mn, long n4) {
  long i = (long)blockIdx.x * blockDim.x + threadIdx.x;
  long stride = (long)gridDim.x * blockDim.x;
  uint4v v = {0x7F800000u, 0x7F800000u, 0x7F800000u, 0x7F800000u};
  for (; i < n4; i += stride) ((uint4v*)mn)[i] = v;
}

// ---- node_feat f32 -> bf16 table -------------------------------------------
__global__ void conv_node_kernel(const float* __restrict__ nf, short* __restrict__ nb, long n4) {
  long i = (long)blockIdx.x * blockDim.x + threadIdx.x;
  long stride = (long)gridDim.x * blockDim.x;
  for (; i < n4; i += stride) {
    float4v v = ((const float4v*)nf)[i];
    short4v s;
    s[0] = f2bf(v[0]); s[1] = f2bf(v[1]); s[2] = f2bf(v[2]); s[3] = f2bf(v[3]);
    ((short4v*)nb)[i] = s;
  }
}

// ---- weights: transpose to [n][k] row-major bf16 ---------------------------
__global__ void conv_w_kernel(const float* __restrict__ Wpre, const float* __restrict__ Wp1,
                              const float* __restrict__ Wp2, short* __restrict__ WpreT,
                              short* __restrict__ Wp1T, short* __restrict__ Wp2T) {
  int idx = blockIdx.x * 256 + threadIdx.x;
  if (idx < 128 * 320) {
    int n = idx / 320, k = idx % 320;
    WpreT[idx] = f2bf(Wpre[k * 128 + n]);
  } else if (idx < 128 * 320 + 128 * 1664) {
    int o = idx - 128 * 320;
    int n = o / 1664, k = o % 1664;
    Wp1T[o] = f2bf(Wp1[k * 128 + n]);
  } else if (idx < 128 * 320 + 128 * 1664 + 128 * 128) {
    int o = idx - (128 * 320 + 128 * 1664);
    int n = o / 128, k = o % 128;
    Wp2T[o] = f2bf(Wp2[k * 128 + n]);
  }
}

// ---- degree histogram ------------------------------------------------------
__global__ void deg_kernel(const int* __restrict__ dst, int* __restrict__ deg) {
  int i = blockIdx.x * blockDim.x + threadIdx.x;
  int stride = gridDim.x * blockDim.x;
  for (; i < N_EDGES; i += stride) atomicAdd(deg + dst[i], 1);
}

// ---- exclusive scan of deg -> cursor (single block, 1024 threads) ----------
__global__ __launch_bounds__(1024) void scan_kernel(const int* __restrict__ deg,
                                                    int* __restrict__ cursor) {
  __shared__ int part[1024];
  const int CH = 49;  // 1024*49 >= 50000
  int t = threadIdx.x;
  int base = t * CH;
  int s = 0;
  for (int i = 0; i < CH; i++) {
    int idx = base + i;
    if (idx < N_NODES) s += deg[idx];
  }
  part[t] = s;
  __syncthreads();
  for (int off = 1; off < 1024; off <<= 1) {
    int v = (t >= off) ? part[t - off] : 0;
    __syncthreads();
    part[t] += v;
    __syncthreads();
  }
  int ex = (t == 0) ? 0 : part[t - 1];
  for (int i = 0; i < CH; i++) {
    int idx = base + i;
    if (idx < N_NODES) {
      cursor[idx] = ex;
      ex += deg[idx];
    }
  }
}

// ---- scatter: perm = edge ids sorted by dst --------------------------------
__global__ void scatter_kernel(const int* __restrict__ dst, int* __restrict__ cursor,
                               int* __restrict__ perm) {
  int i = blockIdx.x * blockDim.x + threadIdx.x;
  int stride = gridDim.x * blockDim.x;
  for (; i < N_EDGES; i += stride) {
    int pos = atomicAdd(cursor + dst[i], 1);
    perm[pos] = i;
  }
}

// ---- edge kernel: sorted edges, MFMA, in-LDS segmented reduction -----------
// Interior segments -> plain stores; chunk-boundary segments -> atomics.
__global__ __launch_bounds__(256) void edge_kernel(
    const int* __restrict__ src, const int* __restrict__ dst,
    const float* __restrict__ edge_feat, const float* __restrict__ b_pre,
    const short* __restrict__ node_bf, const short* __restrict__ WpreT,
    const int* __restrict__ perm,
    float* __restrict__ sum, float* __restrict__ sq,
    unsigned int* __restrict__ mx, unsigned int* __restrict__ mn) {
  __shared__ short A[32][328];   // 32 edges x 320 (pad 8)
  __shared__ float E[32][129];   // post-relu messages (pad 1: reg->LDS col writes)
  __shared__ int pidl[32], srcl[32], dstl[32];
  int t = threadIdx.x;
  int lane = t & 63, w = t >> 6;
  int r15 = lane & 15, g = lane >> 4;

  // preload B fragments: wave w owns n-tiles {2w, 2w+1}
  short8v bfr[10][2];
#pragma unroll
  for (int ks = 0; ks < 10; ks++)
#pragma unroll
    for (int j = 0; j < 2; j++) {
      const short* p = WpreT + (size_t)((2 * w + j) * 16 + r15) * 320 + ks * 32 + 8 * g;
      bfr[ks][j] = *(const short8v*)p;
    }
  float bp[2];
  bp[0] = b_pre[2 * w * 16 + r15];
  bp[1] = b_pre[(2 * w + 1) * 16 + r15];

  const int nchunks = N_EDGES / 32;  // 18750, exact
  for (int ch = blockIdx.x; ch < nchunks; ch += gridDim.x) {
    int e0 = ch * 32;
    __syncthreads();  // prev-iter scan done (E/dstl reusable)
    if (t < 32) {
      int eid = perm[e0 + t];
      pidl[t] = eid;
      srcl[t] = src[eid];
      dstl[t] = dst[eid];
    }
    __syncthreads();

    // gather src|dst node rows (bf16, 512B per edge): 1024 x 16B units
#pragma unroll
    for (int i = 0; i < 4; i++) {
      int u = t + 256 * i;
      int e = u >> 5, off16 = u & 31;
      int idx = (off16 < 16) ? srcl[e] : dstl[e];
      int col16 = off16 & 15;
      *(int4*)(&A[e][off16 * 8]) = *(const int4*)(node_bf + (size_t)idx * 128 + col16 * 8);
    }
    // edge_feat f32 -> bf16 : 512 x 4-float units
#pragma unroll
    for (int i = 0; i < 2; i++) {
      int u = t + 256 * i;
      int e = u >> 4, c4 = (u & 15) * 4;
      float4v v = *(const float4v*)(edge_feat + (size_t)pidl[e] * 64 + c4);
      short4v s;
      s[0] = f2bf(v[0]); s[1] = f2bf(v[1]); s[2] = f2bf(v[2]); s[3] = f2bf(v[3]);
      *(short4v*)(&A[e][256 + c4]) = s;
    }
    __syncthreads();

    f32x4 acc[2][2];
#pragma unroll
    for (int m = 0; m < 2; m++)
#pragma unroll
      for (int j = 0; j < 2; j++) acc[m][j] = (f32x4){0.f, 0.f, 0.f, 0.f};

#pragma unroll
    for (int m = 0; m < 2; m++)
#pragma unroll
      for (int ks = 0; ks < 10; ks++) {
        short8v af = *(const short8v*)(&A[m * 16 + r15][ks * 32 + 8 * g]);
        acc[m][0] = __builtin_amdgcn_mfma_f32_16x16x32_bf16(af, bfr[ks][0], acc[m][0], 0, 0, 0);
        acc[m][1] = __builtin_amdgcn_mfma_f32_16x16x32_bf16(af, bfr[ks][1], acc[m][1], 0, 0, 0);
      }

    // bias + relu -> LDS e-tile
#pragma unroll
    for (int m = 0; m < 2; m++)
#pragma unroll
      for (int j = 0; j < 2; j++)
#pragma unroll
        for (int r = 0; r < 4; r++) {
          float v = fmaxf(acc[m][j][r] + bp[j], 0.f);
          E[m * 16 + 4 * g + r][(2 * w + j) * 16 + r15] = v;
        }
    __syncthreads();

    // segmented reduction over sorted rows: thread = (col, stat-pair)
    {
      int c = t & 127;
      int half = t >> 7;  // 0: sum+sq, 1: max+min
      float a0 = (half == 0) ? 0.f : -__builtin_inff();
      float a1 = (half == 0) ? 0.f : __builtin_inff();
      int s0 = 0;
      for (int r = 0; r < 32; r++) {
        float v = E[r][c];
        if (half == 0) { a0 += v; a1 += v * v; }
        else { a0 = fmaxf(a0, v); a1 = fminf(a1, v); }
        bool flush = (r == 31) || (dstl[r + 1] != dstl[r]);
        if (flush) {
          size_t o = (size_t)dstl[r] * 128 + c;
          bool bnd = (s0 == 0) || (r == 31);  // may continue in neighbor chunk
          if (half == 0) {
            if (bnd) { atomicAdd(sum + o, a0); atomicAdd(sq + o, a1); }
            else { sum[o] = a0; sq[o] = a1; }
            a0 = 0.f; a1 = 0.f;
          } else {
            if (bnd) { atomicMax(mx + o, __float_as_uint(a0)); atomicMin(mn + o, __float_as_uint(a1)); }
            else { ((float*)mx)[o] = a0; ((float*)mn)[o] = a1; }
            a0 = -__builtin_inff(); a1 = __builtin_inff();
          }
          s0 = r + 1;
        }
      }
    }
  }
}

// ---- post kernel: build h[1664] on the fly, 2-layer MLP + residual ---------
__global__ __launch_bounds__(256) void post_kernel(
    const float* __restrict__ node_feat, const int* __restrict__ deg,
    const float* __restrict__ sum, const float* __restrict__ sq,
    const float* __restrict__ mxp, const float* __restrict__ mnp,
    const short* __restrict__ Wp1T, const short* __restrict__ Wp2T,
    const float* __restrict__ b1, const float* __restrict__ b2,
    float* __restrict__ out) {
  __shared__ short Ak[64][40];    // 64 nodes x 32 k (pad 8)
  __shared__ short T[64][136];    // relu(h@W1+b1) bf16 (pad 8)
  __shared__ float scal[64][4];   // inv_safe_deg, logd/2.5, att_factor, has_edges
  int t = threadIdx.x;
  int lane = t & 63, w = t >> 6;
  int r15 = lane & 15, g = lane >> 4;
  int nb = blockIdx.x * 64;

  if (t < 64) {
    int n = min(nb + t, N_NODES - 1);
    float dg = (float)deg[n];
    scal[t][0] = 1.f / fmaxf(dg, 1.f);
    float logd = logf(dg + 1.f);
    scal[t][1] = logd * 0.4f;                                  // /2.5
    scal[t][2] = (dg > 0.f) ? 2.5f / fmaxf(logd, 1e-5f) : 0.f;
    scal[t][3] = (dg > 0.f) ? 1.f : 0.f;
  }
  __syncthreads();

  f32x4 acc1[4][2];
#pragma unroll
  for (int m = 0; m < 4; m++)
#pragma unroll
    for (int j = 0; j < 2; j++) acc1[m][j] = (f32x4){0.f, 0.f, 0.f, 0.f};

  for (int ks = 0; ks < 52; ks++) {
    int k0 = ks * 32;
    int seg = k0 >> 7;     // uniform per k-step (32 | 128)
    int cbase = k0 & 127;
#pragma unroll
    for (int jj = 0; jj < 8; jj++) {
      int vi = t + 256 * jj;
      int nd = vi >> 5, c = vi & 31;
      int gn = min(nb + nd, N_NODES - 1);
      int col = cbase + c;
      float v;
      if (seg == 0) {
        v = node_feat[(size_t)gn * 128 + col];
      } else {
        int si = (seg - 1) & 3, sc = (seg - 1) >> 2;
        size_t o = (size_t)gn * 128 + col;
        float stat;
        if (si == 0) {
          stat = sum[o] * scal[nd][0];                               // mean
        } else if (si == 1) {
          stat = (scal[nd][3] != 0.f) ? mxp[o] : 0.f;                // max
        } else if (si == 2) {
          stat = (scal[nd][3] != 0.f) ? mnp[o] : 0.f;                // min (gate +inf)
        } else {
          float mean = sum[o] * scal[nd][0];
          float ms = sq[o] * scal[nd][0];
          stat = scal[nd][3] * sqrtf(fmaxf(ms - mean * mean, 0.f) + 1e-5f);  // std
        }
        float f = (sc == 0) ? 1.f : ((sc == 1) ? scal[nd][1] : scal[nd][2]);
        v = stat * f;
      }
      Ak[nd][c] = f2bf(v);
    }
    __syncthreads();
    short8v af[4], bfr[2];
#pragma unroll
    for (int m = 0; m < 4; m++) af[m] = *(const short8v*)(&Ak[m * 16 + r15][8 * g]);
#pragma unroll
    for (int j = 0; j < 2; j++)
      bfr[j] = *(const short8v*)(Wp1T + (size_t)((2 * w + j) * 16 + r15) * 1664 + k0 + 8 * g);
#pragma unroll
    for (int m = 0; m < 4; m++)
#pragma unroll
      for (int j = 0; j < 2; j++)
        acc1[m][j] = __builtin_amdgcn_mfma_f32_16x16x32_bf16(af[m], bfr[j], acc1[m][j], 0, 0, 0);
    __syncthreads();
  }

  float bb1[2];
  bb1[0] = b1[2 * w * 16 + r15];
  bb1[1] = b1[(2 * w + 1) * 16 + r15];
#pragma unroll
  for (int m = 0; m < 4; m++)
#pragma unroll
    for (int j = 0; j < 2; j++)
#pragma unroll
      for (int r = 0; r < 4; r++) {
        float v = fmaxf(acc1[m][j][r] + bb1[j], 0.f);
        T[m * 16 + 4 * g + r][(2 * w + j) * 16 + r15] = f2bf(v);
      }
  __syncthreads();

  f32x4 acc2[4][2];
#pragma unroll
  for (int m = 0; m < 4; m++)
#pragma unroll
    for (int j = 0; j < 2; j++) acc2[m][j] = (f32x4){0.f, 0.f, 0.f, 0.f};
#pragma unroll
  for (int ks = 0; ks < 4; ks++) {
    short8v af2[4], b2f[2];
#pragma unroll
    for (int m = 0; m < 4; m++) af2[m] = *(const short8v*)(&T[m * 16 + r15][ks * 32 + 8 * g]);
#pragma unroll
    for (int j = 0; j < 2; j++)
      b2f[j] = *(const short8v*)(Wp2T + (size_t)((2 * w + j) * 16 + r15) * 128 + ks * 32 + 8 * g);
#pragma unroll
    for (int m = 0; m < 4; m++)
#pragma unroll
      for (int j = 0; j < 2; j++)
        acc2[m][j] = __builtin_amdgcn_mfma_f32_16x16x32_bf16(af2[m], b2f[j], acc2[m][j], 0, 0, 0);
  }

#pragma unroll
  for (int m = 0; m < 4; m++)
#pragma unroll
    for (int j = 0; j < 2; j++)
#pragma unroll
      for (int r = 0; r < 4; r++) {
        int row = m * 16 + 4 * g + r;
        int gn = nb + row;
        if (gn < N_NODES) {
          int col = (2 * w + j) * 16 + r15;
          size_t o = (size_t)gn * 128 + col;
          out[o] = acc2[m][j][r] + b2[col] + node_feat[o];
        }
      }
}

extern "C" void kernel_launch(void* const* d_in, const int* in_sizes, int n_in,
                              void* d_out, int out_size, void* d_ws, size_t ws_size,
                              hipStream_t stream) {
  const float* node_feat = (const float*)d_in[0];
  const float* edge_feat = (const float*)d_in[1];
  const int* src = (const int*)d_in[2];
  const int* dst = (const int*)d_in[3];
  const float* W_pre = (const float*)d_in[4];
  const float* b_pre = (const float*)d_in[5];
  const float* W_post1 = (const float*)d_in[6];
  const float* b_post1 = (const float*)d_in[7];
  const float* W_post2 = (const float*)d_in[8];
  const float* b_post2 = (const float*)d_in[9];
  float* out = (float*)d_out;

  char* ws = (char*)d_ws;
  size_t P = (size_t)N_NODES * 128;
  float* sum = (float*)ws;
  float* sq = sum + P;
  float* mx = sq + P;
  float* mn = mx + P;
  int* deg = (int*)(mn + P);
  int* cursor = deg + 50048;
  int* perm = cursor + 50048;
  short* node_bf = (short*)(perm + 600064);
  short* WpreT = node_bf + P;
  short* Wp1T = WpreT + 128 * 320;
  short* Wp2T = Wp1T + 128 * 1664;
  size_t needed = (size_t)((char*)(Wp2T + 128 * 128) - ws);
  if (ws_size < needed) return;  // clean failure signal instead of OOB

  hipMemsetAsync(sum, 0, 3 * P * sizeof(float), stream);  // sum, sq, mx
  hipMemsetAsync(deg, 0, 50000 * sizeof(int), stream);
  fill_mn_kernel<<<2048, 256, 0, stream>>>((unsigned int*)mn, (long)(P / 4));
  conv_node_kernel<<<2048, 256, 0, stream>>>(node_feat, node_bf, (long)(P / 4));
  conv_w_kernel<<<(128 * 320 + 128 * 1664 + 128 * 128 + 255) / 256, 256, 0, stream>>>(
      W_pre, W_post1, W_post2, WpreT, Wp1T, Wp2T);
  deg_kernel<<<1024, 256, 0, stream>>>(dst, deg);
  scan_kernel<<<1, 1024, 0, stream>>>(deg, cursor);
  scatter_kernel<<<1024, 256, 0, stream>>>(dst, cursor, perm);
  edge_kernel<<<1536, 256, 0, stream>>>(src, dst, edge_feat, b_pre, node_bf, WpreT, perm, sum,
                                        sq, (unsigned int*)mx, (unsigned int*)mn);
  post_kernel<<<(N_NODES + 63) / 64, 256, 0, stream>>>(node_feat, deg, sum, sq, mx, mn, Wp1T,
                                                       Wp2T, b_post1, b_post2, out);
}

// Round 4
// 484.578 us; speedup vs baseline: 2.6071x; 1.5061x over previous
//
#include <hip/hip_runtime.h>
#include <hip/hip_bf16.h>
#include <math.h>

#define N_NODES 50000
#define N_EDGES 600000
// IN_DIM=128, EDGE_DIM=64, PRE_K=320, POST_K=1664, OUT=128

typedef __attribute__((ext_vector_type(8))) short short8v;   // 8 bf16 (4 VGPR) MFMA A/B frag
typedef __attribute__((ext_vector_type(4))) short short4v;
typedef __attribute__((ext_vector_type(4))) float f32x4;     // MFMA C/D frag
typedef __attribute__((ext_vector_type(4))) float float4v;
typedef __attribute__((ext_vector_type(4))) unsigned int uint4v;

__device__ __forceinline__ short f2bf(float f) {
  unsigned int u = __float_as_uint(f);
  u = (u + 0x7FFFu + ((u >> 16) & 1u)) >> 16;   // RNE
  return (short)u;
}

// ---- init: mn plane = FLT_MAX (NOT +inf: 0*inf=NaN hazard in post) ---------
__global__ void fill_mn_kernel(unsigned int* __restrict__ mn, long n4) {
  long i = (long)blockIdx.x * blockDim.x + threadIdx.x;
  long stride = (long)gridDim.x * blockDim.x;
  uint4v v = {0x7F7FFFFFu, 0x7F7FFFFFu, 0x7F7FFFFFu, 0x7F7FFFFFu};
  for (; i < n4; i += stride) ((uint4v*)mn)[i] = v;
}

// ---- node_feat f32 -> bf16 table -------------------------------------------
__global__ void conv_node_kernel(const float* __restrict__ nf, short* __restrict__ nb, long n4) {
  long i = (long)blockIdx.x * blockDim.x + threadIdx.x;
  long stride = (long)gridDim.x * blockDim.x;
  for (; i < n4; i += stride) {
    float4v v = ((const float4v*)nf)[i];
    short4v s;
    s[0] = f2bf(v[0]); s[1] = f2bf(v[1]); s[2] = f2bf(v[2]); s[3] = f2bf(v[3]);
    ((short4v*)nb)[i] = s;
  }
}

// ---- weights: transpose to [n][k] row-major bf16 ---------------------------
__global__ void conv_w_kernel(const float* __restrict__ Wpre, const float* __restrict__ Wp1,
                              const float* __restrict__ Wp2, short* __restrict__ WpreT,
                              short* __restrict__ Wp1T, short* __restrict__ Wp2T) {
  int idx = blockIdx.x * 256 + threadIdx.x;
  if (idx < 128 * 320) {
    int n = idx / 320, k = idx % 320;
    WpreT[idx] = f2bf(Wpre[k * 128 + n]);
  } else if (idx < 128 * 320 + 128 * 1664) {
    int o = idx - 128 * 320;
    int n = o / 1664, k = o % 1664;
    Wp1T[o] = f2bf(Wp1[k * 128 + n]);
  } else if (idx < 128 * 320 + 128 * 1664 + 128 * 128) {
    int o = idx - (128 * 320 + 128 * 1664);
    int n = o / 128, k = o % 128;
    Wp2T[o] = f2bf(Wp2[k * 128 + n]);
  }
}

// ---- degree histogram ------------------------------------------------------
__global__ void deg_kernel(const int* __restrict__ dst, int* __restrict__ deg) {
  int i = blockIdx.x * blockDim.x + threadIdx.x;
  int stride = gridDim.x * blockDim.x;
  for (; i < N_EDGES; i += stride) atomicAdd(deg + dst[i], 1);
}

// ---- exclusive scan of deg -> cursor (single block, 1024 threads) ----------
__global__ __launch_bounds__(1024) void scan_kernel(const int* __restrict__ deg,
                                                    int* __restrict__ cursor) {
  __shared__ int part[1024];
  const int CH = 49;  // 1024*49 >= 50000
  int t = threadIdx.x;
  int base = t * CH;
  int s = 0;
  for (int i = 0; i < CH; i++) {
    int idx = base + i;
    if (idx < N_NODES) s += deg[idx];
  }
  part[t] = s;
  __syncthreads();
  for (int off = 1; off < 1024; off <<= 1) {
    int v = (t >= off) ? part[t - off] : 0;
    __syncthreads();
    part[t] += v;
    __syncthreads();
  }
  int ex = (t == 0) ? 0 : part[t - 1];
  for (int i = 0; i < CH; i++) {
    int idx = base + i;
    if (idx < N_NODES) {
      cursor[idx] = ex;
      ex += deg[idx];
    }
  }
}

// ---- scatter: perm = edge ids sorted by dst --------------------------------
__global__ void scatter_kernel(const int* __restrict__ dst, int* __restrict__ cursor,
                               int* __restrict__ perm) {
  int i = blockIdx.x * blockDim.x + threadIdx.x;
  int stride = gridDim.x * blockDim.x;
  for (; i < N_EDGES; i += stride) {
    int pos = atomicAdd(cursor + dst[i], 1);
    perm[pos] = i;
  }
}

// ---- edge kernel: sorted edges, MFMA, in-LDS segmented reduction -----------
__global__ __launch_bounds__(256) void edge_kernel(
    const int* __restrict__ src, const int* __restrict__ dst,
    const float* __restrict__ edge_feat, const float* __restrict__ b_pre,
    const short* __restrict__ node_bf, const short* __restrict__ WpreT,
    const int* __restrict__ perm,
    float* __restrict__ sum, float* __restrict__ sq,
    unsigned int* __restrict__ mx, unsigned int* __restrict__ mn) {
  __shared__ short A[32][328];   // 32 edges x 320 (pad 8)
  __shared__ float E[32][129];   // post-relu messages (pad 1)
  __shared__ int pidl[32], srcl[32], dstl[32];
  int t = threadIdx.x;
  int lane = t & 63, w = t >> 6;
  int r15 = lane & 15, g = lane >> 4;

  short8v bfr[10][2];
#pragma unroll
  for (int ks = 0; ks < 10; ks++)
#pragma unroll
    for (int j = 0; j < 2; j++) {
      const short* p = WpreT + (size_t)((2 * w + j) * 16 + r15) * 320 + ks * 32 + 8 * g;
      bfr[ks][j] = *(const short8v*)p;
    }
  float bp[2];
  bp[0] = b_pre[2 * w * 16 + r15];
  bp[1] = b_pre[(2 * w + 1) * 16 + r15];

  const int nchunks = N_EDGES / 32;  // 18750
  for (int ch = blockIdx.x; ch < nchunks; ch += gridDim.x) {
    int e0 = ch * 32;
    __syncthreads();
    if (t < 32) {
      int eid = perm[e0 + t];
      pidl[t] = eid;
      srcl[t] = src[eid];
      dstl[t] = dst[eid];
    }
    __syncthreads();

#pragma unroll
    for (int i = 0; i < 4; i++) {
      int u = t + 256 * i;
      int e = u >> 5, off16 = u & 31;
      int idx = (off16 < 16) ? srcl[e] : dstl[e];
      int col16 = off16 & 15;
      *(int4*)(&A[e][off16 * 8]) = *(const int4*)(node_bf + (size_t)idx * 128 + col16 * 8);
    }
#pragma unroll
    for (int i = 0; i < 2; i++) {
      int u = t + 256 * i;
      int e = u >> 4, c4 = (u & 15) * 4;
      float4v v = *(const float4v*)(edge_feat + (size_t)pidl[e] * 64 + c4);
      short4v s;
      s[0] = f2bf(v[0]); s[1] = f2bf(v[1]); s[2] = f2bf(v[2]); s[3] = f2bf(v[3]);
      *(short4v*)(&A[e][256 + c4]) = s;
    }
    __syncthreads();

    f32x4 acc[2][2];
#pragma unroll
    for (int m = 0; m < 2; m++)
#pragma unroll
      for (int j = 0; j < 2; j++) acc[m][j] = (f32x4){0.f, 0.f, 0.f, 0.f};

#pragma unroll
    for (int m = 0; m < 2; m++)
#pragma unroll
      for (int ks = 0; ks < 10; ks++) {
        short8v af = *(const short8v*)(&A[m * 16 + r15][ks * 32 + 8 * g]);
        acc[m][0] = __builtin_amdgcn_mfma_f32_16x16x32_bf16(af, bfr[ks][0], acc[m][0], 0, 0, 0);
        acc[m][1] = __builtin_amdgcn_mfma_f32_16x16x32_bf16(af, bfr[ks][1], acc[m][1], 0, 0, 0);
      }

#pragma unroll
    for (int m = 0; m < 2; m++)
#pragma unroll
      for (int j = 0; j < 2; j++)
#pragma unroll
        for (int r = 0; r < 4; r++) {
          float v = fmaxf(acc[m][j][r] + bp[j], 0.f);
          E[m * 16 + 4 * g + r][(2 * w + j) * 16 + r15] = v;
        }
    __syncthreads();

    {
      int c = t & 127;
      int half = t >> 7;  // 0: sum+sq, 1: max+min
      float a0 = (half == 0) ? 0.f : -__builtin_inff();
      float a1 = (half == 0) ? 0.f : __builtin_inff();
      int s0 = 0;
      for (int r = 0; r < 32; r++) {
        float v = E[r][c];
        if (half == 0) { a0 += v; a1 += v * v; }
        else { a0 = fmaxf(a0, v); a1 = fminf(a1, v); }
        bool flush = (r == 31) || (dstl[r + 1] != dstl[r]);
        if (flush) {
          size_t o = (size_t)dstl[r] * 128 + c;
          bool bnd = (s0 == 0) || (r == 31);
          if (half == 0) {
            if (bnd) { atomicAdd(sum + o, a0); atomicAdd(sq + o, a1); }
            else { sum[o] = a0; sq[o] = a1; }
            a0 = 0.f; a1 = 0.f;
          } else {
            if (bnd) { atomicMax(mx + o, __float_as_uint(a0)); atomicMin(mn + o, __float_as_uint(a1)); }
            else { ((float*)mx)[o] = a0; ((float*)mn)[o] = a1; }
            a0 = -__builtin_inff(); a1 = __builtin_inff();
          }
          s0 = r + 1;
        }
      }
    }
  }
}

// ---- post kernel: scaler-factored GEMM over K=640 (x | agg), fused MLP2 ----
// h@W1 = x@W1[0:128] + agg@W1[128:640] + ampf*(agg@W1[640:1152]) + attf*(agg@W1[1152:1664])
__global__ __launch_bounds__(256) void post_kernel(
    const float* __restrict__ node_feat, const int* __restrict__ deg,
    const float* __restrict__ sum, const float* __restrict__ sq,
    const float* __restrict__ mxp, const float* __restrict__ mnp,
    const short* __restrict__ node_bf,
    const short* __restrict__ Wp1T, const short* __restrict__ Wp2T,
    const float* __restrict__ b1, const float* __restrict__ b2,
    float* __restrict__ out) {
  __shared__ short Ab[2][64][64];  // double-buffered 64-node x 64-k tile (XOR-swizzled 16B slots)
  __shared__ short T[64][136];     // relu(h@W1+b1) bf16 (pad 8)
  __shared__ float scalL[64][4];   // inv_safe_deg, ampf, attf, has
  int t = threadIdx.x;
  int lane = t & 63, w = t >> 6;
  int r15 = lane & 15, g = lane >> 4;
  int nb = blockIdx.x * 64;

  if (t < 64) {
    int n = min(nb + t, N_NODES - 1);
    float dg = (float)deg[n];
    scalL[t][0] = 1.f / fmaxf(dg, 1.f);
    float logd = logf(dg + 1.f);
    scalL[t][1] = logd * 0.4f;                                   // amp factor
    scalL[t][2] = (dg > 0.f) ? 2.5f / fmaxf(logd, 1e-5f) : 0.f;  // att factor
    scalL[t][3] = (dg > 0.f) ? 1.f : 0.f;
  }
  float bb1[2];
  bb1[0] = b1[2 * w * 16 + r15];
  bb1[1] = b1[(2 * w + 1) * 16 + r15];

  f32x4 accB[4][2], accC[4][2], accD[4][2];
#pragma unroll
  for (int m = 0; m < 4; m++)
#pragma unroll
    for (int j = 0; j < 2; j++) {
      accB[m][j] = (f32x4){0.f, 0.f, 0.f, 0.f};
      accC[m][j] = (f32x4){0.f, 0.f, 0.f, 0.f};
      accD[m][j] = (f32x4){0.f, 0.f, 0.f, 0.f};
    }

  // chunk c: c<2 -> x cols c*64..; c>=2 -> agg stat si=(c-2)>>1 [mean,max,min,std], half=c&1
  auto STAGE = [&](int buf, int c) {
#pragma unroll
    for (int i = 0; i < 2; i++) {
      int row = i * 32 + (t >> 3);
      int gn = min(nb + row, N_NODES - 1);
      int s8 = t & 7;
      short* lp = &Ab[buf][0][0] + row * 64 + (s8 ^ (row & 7)) * 8;
      if (c < 2) {
        *(int4*)lp = *(const int4*)(node_bf + (size_t)gn * 128 + c * 64 + s8 * 8);
      } else {
        size_t o = (size_t)gn * 128 + (c & 1) * 64 + s8 * 8;
        int si = (c - 2) >> 1;
        float inv = scalL[row][0], has = scalL[row][3];
        short8v pk;
        if (si == 0) {
          float4v a = *(const float4v*)(sum + o), b = *(const float4v*)(sum + o + 4);
#pragma unroll
          for (int r = 0; r < 4; r++) { pk[r] = f2bf(a[r] * inv); pk[4 + r] = f2bf(b[r] * inv); }
        } else if (si == 1) {
          float4v a = *(const float4v*)(mxp + o), b = *(const float4v*)(mxp + o + 4);
#pragma unroll
          for (int r = 0; r < 4; r++) { pk[r] = f2bf(a[r]); pk[4 + r] = f2bf(b[r]); }
        } else if (si == 2) {
          float4v a = *(const float4v*)(mnp + o), b = *(const float4v*)(mnp + o + 4);
          bool h = (has != 0.f);  // SELECT, not multiply: 0*FLT_MAX safe, but 0*inf was NaN
#pragma unroll
          for (int r = 0; r < 4; r++) {
            pk[r] = f2bf(h ? a[r] : 0.f);
            pk[4 + r] = f2bf(h ? b[r] : 0.f);
          }
        } else {
          float4v a = *(const float4v*)(sum + o), b = *(const float4v*)(sum + o + 4);
          float4v qa = *(const float4v*)(sq + o), qb = *(const float4v*)(sq + o + 4);
#pragma unroll
          for (int r = 0; r < 4; r++) {
            float m0 = a[r] * inv, m1 = b[r] * inv;
            pk[r] = f2bf(has * sqrtf(fmaxf(qa[r] * inv - m0 * m0, 0.f) + 1e-5f));
            pk[4 + r] = f2bf(has * sqrtf(fmaxf(qb[r] * inv - m1 * m1, 0.f) + 1e-5f));
          }
        }
        *(short8v*)lp = pk;
      }
    }
  };

  auto COMPUTE = [&](int buf, int c) {
    const short* base = &Ab[buf][0][0];
#pragma unroll
    for (int ks2 = 0; ks2 < 2; ks2++) {
      short8v af[4];
#pragma unroll
      for (int m = 0; m < 4; m++) {
        int row = m * 16 + r15;
        af[m] = *(const short8v*)(base + row * 64 + (((ks2 << 2) | g) ^ (row & 7)) * 8);
      }
      if (c < 2) {
        int kcol = c * 64 + ks2 * 32;
#pragma unroll
        for (int j = 0; j < 2; j++) {
          short8v bf = *(const short8v*)(Wp1T + (size_t)((2 * w + j) * 16 + r15) * 1664 + kcol + 8 * g);
#pragma unroll
          for (int m = 0; m < 4; m++)
            accB[m][j] = __builtin_amdgcn_mfma_f32_16x16x32_bf16(af[m], bf, accB[m][j], 0, 0, 0);
        }
      } else {
        int kagg = (c - 2) * 64 + ks2 * 32;
#pragma unroll
        for (int j = 0; j < 2; j++) {
          const short* wr = Wp1T + (size_t)((2 * w + j) * 16 + r15) * 1664 + 8 * g;
          short8v bb = *(const short8v*)(wr + 128 + kagg);
          short8v bc = *(const short8v*)(wr + 640 + kagg);
          short8v bd = *(const short8v*)(wr + 1152 + kagg);
#pragma unroll
          for (int m = 0; m < 4; m++) {
            accB[m][j] = __builtin_amdgcn_mfma_f32_16x16x32_bf16(af[m], bb, accB[m][j], 0, 0, 0);
            accC[m][j] = __builtin_amdgcn_mfma_f32_16x16x32_bf16(af[m], bc, accC[m][j], 0, 0, 0);
            accD[m][j] = __builtin_amdgcn_mfma_f32_16x16x32_bf16(af[m], bd, accD[m][j], 0, 0, 0);
          }
        }
      }
    }
  };

  STAGE(0, 0);
  __syncthreads();
#pragma unroll
  for (int c = 0; c < 10; c++) {
    if (c < 9) STAGE((c + 1) & 1, c + 1);
    COMPUTE(c & 1, c);
    __syncthreads();
  }

  // combine with per-node scalers, bias, relu -> T (bf16)
#pragma unroll
  for (int m = 0; m < 4; m++)
#pragma unroll
    for (int j = 0; j < 2; j++)
#pragma unroll
      for (int r = 0; r < 4; r++) {
        int row = m * 16 + 4 * g + r;
        float v = accB[m][j][r] + scalL[row][1] * accC[m][j][r] + scalL[row][2] * accD[m][j][r] +
                  bb1[j];
        T[row][(2 * w + j) * 16 + r15] = f2bf(fmaxf(v, 0.f));
      }
  __syncthreads();

  f32x4 acc2[4][2];
#pragma unroll
  for (int m = 0; m < 4; m++)
#pragma unroll
    for (int j = 0; j < 2; j++) acc2[m][j] = (f32x4){0.f, 0.f, 0.f, 0.f};
#pragma unroll
  for (int ks = 0; ks < 4; ks++) {
    short8v af2[4], b2f[2];
#pragma unroll
    for (int m = 0; m < 4; m++) af2[m] = *(const short8v*)(&T[m * 16 + r15][ks * 32 + 8 * g]);
#pragma unroll
    for (int j = 0; j < 2; j++)
      b2f[j] = *(const short8v*)(Wp2T + (size_t)((2 * w + j) * 16 + r15) * 128 + ks * 32 + 8 * g);
#pragma unroll
    for (int m = 0; m < 4; m++)
#pragma unroll
      for (int j = 0; j < 2; j++)
        acc2[m][j] = __builtin_amdgcn_mfma_f32_16x16x32_bf16(af2[m], b2f[j], acc2[m][j], 0, 0, 0);
  }

#pragma unroll
  for (int m = 0; m < 4; m++)
#pragma unroll
    for (int j = 0; j < 2; j++)
#pragma unroll
      for (int r = 0; r < 4; r++) {
        int row = m * 16 + 4 * g + r;
        int gn = nb + row;
        if (gn < N_NODES) {
          int col = (2 * w + j) * 16 + r15;
          size_t o = (size_t)gn * 128 + col;
          out[o] = acc2[m][j][r] + b2[col] + node_feat[o];
        }
      }
}

extern "C" void kernel_launch(void* const* d_in, const int* in_sizes, int n_in,
                              void* d_out, int out_size, void* d_ws, size_t ws_size,
                              hipStream_t stream) {
  const float* node_feat = (const float*)d_in[0];
  const float* edge_feat = (const float*)d_in[1];
  const int* src = (const int*)d_in[2];
  const int* dst = (const int*)d_in[3];
  const float* W_pre = (const float*)d_in[4];
  const float* b_pre = (const float*)d_in[5];
  const float* W_post1 = (const float*)d_in[6];
  const float* b_post1 = (const float*)d_in[7];
  const float* W_post2 = (const float*)d_in[8];
  const float* b_post2 = (const float*)d_in[9];
  float* out = (float*)d_out;

  char* ws = (char*)d_ws;
  size_t P = (size_t)N_NODES * 128;
  float* sum = (float*)ws;
  float* sq = sum + P;
  float* mx = sq + P;
  float* mn = mx + P;
  int* deg = (int*)(mn + P);
  int* cursor = deg + 50048;
  int* perm = cursor + 50048;
  short* node_bf = (short*)(perm + 600064);
  short* WpreT = node_bf + P;
  short* Wp1T = WpreT + 128 * 320;
  short* Wp2T = Wp1T + 128 * 1664;
  size_t needed = (size_t)((char*)(Wp2T + 128 * 128) - ws);
  if (ws_size < needed) return;  // clean failure signal instead of OOB

  hipMemsetAsync(sum, 0, 3 * P * sizeof(float), stream);  // sum, sq, mx
  hipMemsetAsync(deg, 0, 50000 * sizeof(int), stream);
  fill_mn_kernel<<<2048, 256, 0, stream>>>((unsigned int*)mn, (long)(P / 4));
  conv_node_kernel<<<2048, 256, 0, stream>>>(node_feat, node_bf, (long)(P / 4));
  conv_w_kernel<<<(128 * 320 + 128 * 1664 + 128 * 128 + 255) / 256, 256, 0, stream>>>(
      W_pre, W_post1, W_post2, WpreT, Wp1T, Wp2T);
  deg_kernel<<<1024, 256, 0, stream>>>(dst, deg);
  scan_kernel<<<1, 1024, 0, stream>>>(deg, cursor);
  scatter_kernel<<<1024, 256, 0, stream>>>(dst, cursor, perm);
  edge_kernel<<<1536, 256, 0, stream>>>(src, dst, edge_feat, b_pre, node_bf, WpreT, perm, sum,
                                        sq, (unsigned int*)mx, (unsigned int*)mn);
  post_kernel<<<(N_NODES + 63) / 64, 256, 0, stream>>>(node_feat, deg, sum, sq, mx, mn, node_bf,
                                                       Wp1T, Wp2T, b_post1, b_post2, out);
}